// Round 10
// baseline (436.342 us; speedup 1.0000x reference)
//
#include <hip/hip_runtime.h>

// Morphological dilation (max-plus 3x3 conv), zero-padded.
// x: (B=4, C=64, H=512, W=512) fp32, weights: (C=64, 3, 3) fp32.
// out[b,c,h,w] = max_{i,j in 0..2} ( xp[b,c,h-1+i,w-1+j] + wt[c,i,j] ),
// zero-padded (nn.Unfold semantics) — padded zeros DO participate.
//
// R9: 4(rows)x8(cols) tile per thread; ALL loads are aligned dwordx4.
// Per input row: L(w8-4), A(w8), B(w8+4), R(w8+8). Halo words are L.w
// and R.x; lanes wi==0 / wi==63 clamp the OOB address and cndmask the
// pad column to 0. 24 loads + 8 stores per 256B of output (R8 was
// 38 per 128B): -58% VMEM instructions per byte, zero scalar loads,
// zero lane divergence. Plain cached stores.

#define BB 4
#define CC 64
#define HH 512
#define WW 512
#define W8 (WW / 8)   // 64 col-groups -> one wave covers a full row
#define RB 4          // output rows per thread
#define HB (HH / RB)  // 128 row-blocks

typedef float vfloat4 __attribute__((ext_vector_type(4)));

__global__ __launch_bounds__(256) void morph_dilate_kernel(
    const float* __restrict__ x,
    const float* __restrict__ wts,
    float* __restrict__ out) {
    int tid = blockIdx.x * blockDim.x + threadIdx.x;
    // total threads = 256 planes * 128 hb * 64 wi = 2,097,152
    int wi    = tid & (W8 - 1);          // col-group 0..63 (== lane)
    int w8    = wi * 8;
    int hb    = (tid >> 6) & (HB - 1);   // row-block (wave-uniform)
    int h0    = hb * RB;
    int plane = tid >> 13;               // b*C + c (wave-uniform)
    int c     = plane & (CC - 1);

    const float* xplane = x + (size_t)plane * (HH * WW);
    const float* wt = wts + c * 9;

    float w00 = wt[0], w01 = wt[1], w02 = wt[2];
    float w10 = wt[3], w11 = wt[4], w12 = wt[5];
    float w20 = wt[6], w21 = wt[7], w22 = wt[8];

    bool isl = (wi == 0);
    bool isr = (wi == W8 - 1);
    int offL = isl ? 0        : (w8 - 4);   // clamped aligned x4 address
    int offR = isr ? (w8 + 4) : (w8 + 8);

    // 6 input rows (h0-1 .. h0+4), 10-float window cols w8-1 .. w8+8
    float v[6][10];
#pragma unroll
    for (int i = 0; i < 6; ++i) {
        int r = h0 - 1 + i;               // wave-uniform condition
        if (r >= 0 && r < HH) {
            const float* xrow = xplane + r * WW;
            vfloat4 L = *reinterpret_cast<const vfloat4*>(xrow + offL);
            vfloat4 A = *reinterpret_cast<const vfloat4*>(xrow + w8);
            vfloat4 Bv = *reinterpret_cast<const vfloat4*>(xrow + w8 + 4);
            vfloat4 R = *reinterpret_cast<const vfloat4*>(xrow + offR);
            v[i][0] = isl ? 0.0f : L.w;
            v[i][1] = A.x; v[i][2] = A.y; v[i][3] = A.z; v[i][4] = A.w;
            v[i][5] = Bv.x; v[i][6] = Bv.y; v[i][7] = Bv.z; v[i][8] = Bv.w;
            v[i][9] = isr ? 0.0f : R.x;
        } else {
#pragma unroll
            for (int j = 0; j < 10; ++j) v[i][j] = 0.0f;
        }
    }

    float* oplane = out + (size_t)plane * (HH * WW);
#pragma unroll
    for (int rt = 0; rt < RB; ++rt) {
        vfloat4 o0, o1;
#pragma unroll
        for (int t = 0; t < 4; ++t) {
            float m;
            m =          v[rt + 0][t + 0] + w00;
            m = fmaxf(m, v[rt + 0][t + 1] + w01);
            m = fmaxf(m, v[rt + 0][t + 2] + w02);
            m = fmaxf(m, v[rt + 1][t + 0] + w10);
            m = fmaxf(m, v[rt + 1][t + 1] + w11);
            m = fmaxf(m, v[rt + 1][t + 2] + w12);
            m = fmaxf(m, v[rt + 2][t + 0] + w20);
            m = fmaxf(m, v[rt + 2][t + 1] + w21);
            m = fmaxf(m, v[rt + 2][t + 2] + w22);
            o0[t] = m;
        }
#pragma unroll
        for (int t = 4; t < 8; ++t) {
            float m;
            m =          v[rt + 0][t + 0] + w00;
            m = fmaxf(m, v[rt + 0][t + 1] + w01);
            m = fmaxf(m, v[rt + 0][t + 2] + w02);
            m = fmaxf(m, v[rt + 1][t + 0] + w10);
            m = fmaxf(m, v[rt + 1][t + 1] + w11);
            m = fmaxf(m, v[rt + 1][t + 2] + w12);
            m = fmaxf(m, v[rt + 2][t + 0] + w20);
            m = fmaxf(m, v[rt + 2][t + 1] + w21);
            m = fmaxf(m, v[rt + 2][t + 2] + w22);
            o1[t - 4] = m;
        }
        float* orow = oplane + (size_t)(h0 + rt) * WW + w8;
        *reinterpret_cast<vfloat4*>(orow) = o0;
        *reinterpret_cast<vfloat4*>(orow + 4) = o1;
    }
}

extern "C" void kernel_launch(void* const* d_in, const int* in_sizes, int n_in,
                              void* d_out, int out_size, void* d_ws, size_t ws_size,
                              hipStream_t stream) {
    const float* x   = (const float*)d_in[0];
    const float* wts = (const float*)d_in[1];
    float* out = (float*)d_out;

    int total_threads = BB * CC * HB * W8;   // 2,097,152
    int block = 256;
    int grid = total_threads / block;        // 8,192
    morph_dilate_kernel<<<grid, block, 0, stream>>>(x, wts, out);
}